// Round 16
// baseline (335.116 us; speedup 1.0000x reference)
//
#include <hip/hip_runtime.h>
#include <math.h>

#define SCALE_ 0.08838834764831845f  // 128^-0.5
#define LOG2E_ 1.4426950408889634f

typedef __attribute__((ext_vector_type(4))) float f32x4;
typedef __attribute__((ext_vector_type(8))) short sh8;   // 8 bf16 in 4 VGPRs
typedef __attribute__((ext_vector_type(4))) short sh4;
typedef __attribute__((ext_vector_type(8))) _Float16 hf8; // 8 fp16 in 4 VGPRs
typedef __attribute__((ext_vector_type(2))) unsigned uv2;

static __device__ __forceinline__ short f2bf(float f) {
    union { float f; unsigned u; } v; v.f = f;
    unsigned r = v.u + 0x7fffu + ((v.u >> 16) & 1u);   // RNE
    return (short)(r >> 16);
}
static __device__ __forceinline__ float bf2f(short s) {
    union { unsigned u; float f; } v; v.u = ((unsigned)(unsigned short)s) << 16;
    return v.f;
}
// raw 2^x (v_exp_f32)
static __device__ __forceinline__ float fexp2(float x) {
    float r; asm("v_exp_f32 %0, %1" : "=v"(r) : "v"(x)); return r;
}
// pack 2 f32 -> 2 fp16 with RNE (RTZ bias failed absmax in R6)
static __device__ __forceinline__ unsigned pk2h(float a, float b) {
    union { _Float16 h[2]; unsigned u; } c;
    c.h[0] = (_Float16)a; c.h[1] = (_Float16)b;
    return c.u;
}

// async global->LDS, 16B per lane; LDS dest = wave-uniform base + lane*16
static __device__ __forceinline__ void gl2lds16(const void* g, void* l) {
    __builtin_amdgcn_global_load_lds(
        (const __attribute__((address_space(1))) void*)g,
        (__attribute__((address_space(3))) void*)l, 16, 0, 0);
}

// ---------------------------------------------------------------------------
// Merged preprocessing (R11, passing):
//   blocks [0, 8192)        : hs fp32 -> bf16
//   blocks [8192, 9728)     : transpose+convert QKV weights -> WT bf16
//   blocks [9728, 10752)    : transpose+convert Wo -> WoT fp16
// ---------------------------------------------------------------------------
__global__ __launch_bounds__(256) void prep_kernel(
    const float* __restrict__ hs, short* __restrict__ hs_bf,
    const float* __restrict__ Wq, const float* __restrict__ Wk,
    const float* __restrict__ Wv, short* __restrict__ WT,
    const float* __restrict__ Wo, _Float16* __restrict__ WoT)
{
    __shared__ __align__(16) float Ls[64][65];
    const int bid = blockIdx.x;
    const int tid = threadIdx.x;

    if (bid < 8192) {
        const int i = bid * 256 + tid;
        float4 v = *(const float4*)(hs + (size_t)i * 4);
        sh4 o; o.x = f2bf(v.x); o.y = f2bf(v.y); o.z = f2bf(v.z); o.w = f2bf(v.w);
        *(sh4*)(hs_bf + (size_t)i * 4) = o;
        return;
    }

    if (bid < 9728) {
        const int f  = bid - 8192;
        const int k0 = (f & 31) * 64;
        const int n0 = (f >> 5) * 64;

        const float* src; int ld, col0;
        if (n0 < 2048)      { src = Wq; ld = 2048; col0 = n0; }
        else if (n0 < 2560) { src = Wk; ld = 512;  col0 = n0 - 2048; }
        else                { src = Wv; ld = 512;  col0 = n0 - 2560; }

        for (int i = tid; i < 1024; i += 256) {
            int r = i >> 4, c4 = (i & 15) * 4;
            float4 v = *(const float4*)(src + (size_t)(k0 + r) * ld + col0 + c4);
            Ls[r][c4] = v.x; Ls[r][c4 + 1] = v.y; Ls[r][c4 + 2] = v.z; Ls[r][c4 + 3] = v.w;
        }
        __syncthreads();
        for (int i = tid; i < 512; i += 256) {
            int nl = i >> 3, kk = (i & 7) * 8;
            sh8 v;
            #pragma unroll
            for (int j = 0; j < 8; j++) v[j] = f2bf(Ls[kk + j][nl]);
            *(sh8*)(WT + (size_t)(n0 + nl) * 2048 + k0 + kk) = v;
        }
        return;
    }

    {
        const int f  = bid - 9728;
        const int k0 = (f & 31) * 64;
        const int n0 = (f >> 5) * 64;

        for (int i = tid; i < 1024; i += 256) {
            int r = i >> 4, c4 = (i & 15) * 4;
            float4 v = *(const float4*)(Wo + (size_t)(k0 + r) * 2048 + n0 + c4);
            Ls[r][c4] = v.x; Ls[r][c4 + 1] = v.y; Ls[r][c4 + 2] = v.z; Ls[r][c4 + 3] = v.w;
        }
        __syncthreads();
        for (int i = tid; i < 512; i += 256) {
            int nl = i >> 3, kk = (i & 7) * 8;
            hf8 v;
            #pragma unroll
            for (int j = 0; j < 8; j++) v[j] = (_Float16)Ls[kk + j][nl];
            *(hf8*)(WoT + (size_t)(n0 + nl) * 2048 + k0 + kk) = v;
        }
    }
}

// ---------------------------------------------------------------------------
// QKV GEMM v3 (R12 EXACT, passing, best measured): 256x256 tile, BK=32,
// 8 waves, counted-vmcnt pipeline (T3/T4): 4-buffer LDS rotation, stage t+2
// during t, vmcnt(4) + raw s_barrier (t+2's loads in flight across barrier).
// ---------------------------------------------------------------------------
__global__ __launch_bounds__(512) void gemm_qkv_mfma(
    const short* __restrict__ Abf, const short* __restrict__ Bt,
    const float* __restrict__ bq, const float* __restrict__ bk,
    const float* __restrict__ bv,
    short* __restrict__ Q, short* __restrict__ K, _Float16* __restrict__ V)
{
    __shared__ short As[4][256 * 32];   // 64 KB
    __shared__ short Bs[4][256 * 32];   // 64 KB

    const int tid  = threadIdx.x;
    const int w    = tid >> 6, lane = tid & 63;
    const int l16  = lane & 15, quad = lane >> 4;
    const int wm   = w & 1, wn = w >> 1;      // 2M x 4N waves

    const int bid = blockIdx.x;               // 192 = 16m x 12n, m-major
    const int m0  = (bid & 15) * 256;
    const int n0  = (bid >> 4) * 256;

    const short* agA[2]; const short* agB[2];
    #pragma unroll
    for (int j = 0; j < 2; ++j) {
        const int row = 32 * w + 16 * j + (lane >> 2);
        const int ch  = (lane & 3) * 8;
        agA[j] = Abf + (size_t)(m0 + row) * 2048 + ch;
        agB[j] = Bt  + (size_t)(n0 + row) * 2048 + ch;
    }
    const int doff0 = (32 * w) * 32;
    const int doff1 = (32 * w + 16) * 32;

    f32x4 acc[8][4];
    #pragma unroll
    for (int i = 0; i < 8; ++i)
        #pragma unroll
        for (int j = 0; j < 4; ++j) { acc[i][j].x = 0.f; acc[i][j].y = 0.f; acc[i][j].z = 0.f; acc[i][j].w = 0.f; }

    gl2lds16(agA[0], &As[0][doff0]); gl2lds16(agB[0], &Bs[0][doff0]);
    gl2lds16(agA[1], &As[0][doff1]); gl2lds16(agB[1], &Bs[0][doff1]);
    gl2lds16(agA[0] + 32, &As[1][doff0]); gl2lds16(agB[0] + 32, &Bs[1][doff0]);
    gl2lds16(agA[1] + 32, &As[1][doff1]); gl2lds16(agB[1] + 32, &Bs[1][doff1]);
    asm volatile("s_waitcnt vmcnt(4)" ::: "memory");
    __builtin_amdgcn_s_barrier();

    for (int t = 0; t < 64; ++t) {
        const int cur = t & 3;
        const short* curA = &As[cur][0];
        const short* curB = &Bs[cur][0];

        sh8 bf_[4];
        #pragma unroll
        for (int nt = 0; nt < 4; ++nt)
            bf_[nt] = *(const sh8*)&curB[(wn * 64 + nt * 16 + l16) * 32 + quad * 8];

        sh8 af0[4];
        #pragma unroll
        for (int mt = 0; mt < 4; ++mt)
            af0[mt] = *(const sh8*)&curA[(wm * 128 + mt * 16 + l16) * 32 + quad * 8];
        if (t + 2 < 64) {
            const int nb = (t + 2) & 3;
            gl2lds16(agA[0] + (t + 2) * 32, &As[nb][doff0]);
            gl2lds16(agB[0] + (t + 2) * 32, &Bs[nb][doff0]);
        }
        __builtin_amdgcn_s_setprio(1);
        #pragma unroll
        for (int mt = 0; mt < 4; ++mt)
            #pragma unroll
            for (int nt = 0; nt < 4; ++nt)
                acc[mt][nt] = __builtin_amdgcn_mfma_f32_16x16x32_bf16(af0[mt], bf_[nt], acc[mt][nt], 0, 0, 0);
        __builtin_amdgcn_s_setprio(0);

        sh8 af1[4];
        #pragma unroll
        for (int mt = 0; mt < 4; ++mt)
            af1[mt] = *(const sh8*)&curA[(wm * 128 + (mt + 4) * 16 + l16) * 32 + quad * 8];
        if (t + 2 < 64) {
            const int nb = (t + 2) & 3;
            gl2lds16(agA[1] + (t + 2) * 32, &As[nb][doff1]);
            gl2lds16(agB[1] + (t + 2) * 32, &Bs[nb][doff1]);
        }
        __builtin_amdgcn_s_setprio(1);
        #pragma unroll
        for (int mt = 0; mt < 4; ++mt)
            #pragma unroll
            for (int nt = 0; nt < 4; ++nt)
                acc[mt + 4][nt] = __builtin_amdgcn_mfma_f32_16x16x32_bf16(af1[mt], bf_[nt], acc[mt + 4][nt], 0, 0, 0);
        __builtin_amdgcn_s_setprio(0);

        if (t < 62)       asm volatile("s_waitcnt vmcnt(4)" ::: "memory");
        else if (t == 62) asm volatile("s_waitcnt vmcnt(0)" ::: "memory");
        if (t < 63) __builtin_amdgcn_s_barrier();
    }

    #pragma unroll
    for (int nt = 0; nt < 4; ++nt) {
        const int n_g = n0 + wn * 64 + nt * 16 + l16;
        const int dl  = n_g & 127;
        int which, head; float bv_;
        if (n_g < 2048)      { which = 0; head = n_g >> 7;          bv_ = bq[n_g]; }
        else if (n_g < 2560) { which = 1; head = (n_g - 2048) >> 7; bv_ = bk[n_g - 2048]; }
        else                 { which = 2; head = (n_g - 2560) >> 7; bv_ = bv[n_g - 2560]; }
        #pragma unroll
        for (int mt = 0; mt < 8; ++mt) {
            #pragma unroll
            for (int reg = 0; reg < 4; ++reg) {
                const int m = m0 + wm * 128 + mt * 16 + quad * 4 + reg;
                const int bb = m >> 11, ts = m & 2047;
                const float fv = acc[mt][nt][reg] + bv_;
                if (which == 0)      Q[((size_t)(bb * 16 + head) * 2048 + ts) * 128 + dl] = f2bf(fv);
                else if (which == 1) K[((size_t)(bb * 4 + head) * 2048 + ts) * 128 + dl] = f2bf(fv);
                else                 V[((size_t)(bb * 4 + head) * 2048 + ts) * 128 + dl] = (_Float16)fv;
            }
        }
    }
}

// ---------------------------------------------------------------------------
// Merged RoPE + V-transpose (R11, passing):
//   blocks [0, 2480)    : RoPE in-place on Q,K (vectorized sh8)
//   blocks [2480, 2736) : transpose V (B,KV,T,D) -> Vt (B,KV,D,T)
// ---------------------------------------------------------------------------
__global__ __launch_bounds__(256) void rope_tv_kernel(
    short* __restrict__ Q, short* __restrict__ K,
    const float* __restrict__ cosp, const float* __restrict__ sinp,
    const short* __restrict__ Vb, short* __restrict__ Vt)
{
    __shared__ __align__(16) short Ls[64][136];
    const int bid = blockIdx.x;
    const int tid = threadIdx.x;

    if (bid < 2480) {
        int idx = bid * 256 + tid;
        if (idx >= 2 * 1984 * 20 * 8) return;
        const int j    = idx & 7;
        const int r1   = idx >> 3;
        const int head = r1 % 20;
        const int r2   = r1 / 20;
        const int tt   = r2 % 1984;
        const int b    = r2 / 1984;
        const int t    = 64 + tt;

        const float* cb = cosp + ((size_t)b * 1984 + tt) * 128 + j * 8;
        const float* sb = sinp + ((size_t)b * 1984 + tt) * 128 + j * 8;

        short* base;
        if (head < 16) base = Q + ((size_t)(b * 16 + head)        * 2048 + t) * 128 + j * 8;
        else           base = K + ((size_t)(b * 4  + (head - 16)) * 2048 + t) * 128 + j * 8;

        sh8 x1 = *(const sh8*)base;
        sh8 x2 = *(const sh8*)(base + 64);
        sh8 o1, o2;
        #pragma unroll
        for (int u = 0; u < 8; u++) {
            const float a  = bf2f(x1[u]);
            const float bb = bf2f(x2[u]);
            o1[u] = f2bf(a  * cb[u]      - bb * sb[u]);
            o2[u] = f2bf(bb * cb[u + 64] + a  * sb[u + 64]);
        }
        *(sh8*)base        = o1;
        *(sh8*)(base + 64) = o2;
        return;
    }

    {
        const int f   = bid - 2480;
        const int bkv = f >> 5;
        const int t0  = (f & 31) * 64;

        const short* src = Vb + ((size_t)bkv * 2048 + t0) * 128;
        for (int i = tid; i < 1024; i += 256) {
            int r = i >> 4, c = (i & 15) * 8;
            *(sh8*)&Ls[r][c] = *(const sh8*)(src + (size_t)r * 128 + c);
        }
        __syncthreads();
        short* dst = Vt + (size_t)bkv * 128 * 2048 + t0;
        for (int i = tid; i < 1024; i += 256) {
            int d = i >> 3, c = (i & 7) * 8;
            sh8 v;
            #pragma unroll
            for (int j = 0; j < 8; j++) v[j] = Ls[c + j][d];
            *(sh8*)(dst + (size_t)d * 2048 + c) = v;
        }
    }
}

// ---------------------------------------------------------------------------
// Flash attention v11: KVBLK=128 (R16). Exact v9b 2-barrier lockstep
// skeleton, K-tile doubled 64->128 keys: barrier count halves (32 vs 64),
// amortizing the lockstep drain that is ~25% of attn time. LDS 68KB (free:
// 1 block/CU pinned by unified-reg cap, R1). Prefetch regs double (fine:
// 2 waves/SIMD => 256 VGPR/wave budget). Per-64-key-half mask classes keep
// the v9b logic exactly (diagonal rows provably >= 64).
// ---------------------------------------------------------------------------
#define M0_ 14.0f

__global__ __launch_bounds__(512) void attn_mfma(
    const short* __restrict__ Qb, const short* __restrict__ Kb,
    const short* __restrict__ Vt, _Float16* __restrict__ AOf)
{
    __shared__ __align__(16) short Ks[128][136];    // [key][d] bf16  34816 B
    __shared__ __align__(16) short Vts[128][136];   // [d][key] fp16  34816 B

    const int tid  = threadIdx.x;
    const int qt   = blockIdx.x;
    const int h    = blockIdx.y;
    const int b    = blockIdx.z;
    const int kvh  = h >> 2;
    const int w    = tid >> 6;
    const int lane = tid & 63;
    const int l16  = lane & 15;
    const int quad = lane >> 4;

    const float SC2 = SCALE_ * LOG2E_;
    const float B2A = (1.0f - M0_) * LOG2E_;
    const float B2M = (-M0_) * LOG2E_;

    const short* Kp = Kb + ((size_t)(b * 4 + kvh) * 2048) * 128;
    const short* Vp = Vt + ((size_t)(b * 4 + kvh) * 128) * 2048;

    // staging: thread covers 4 16B chunks of K and of V^T per 128-key tile
    int krow[4], koff[4];
    #pragma unroll
    for (int j = 0; j < 4; j++) {
        const int c = tid + 512 * j;
        krow[j] = c >> 4; koff[j] = (c & 15) * 8;
    }

    sh8 qfrag[2][4];
    #pragma unroll
    for (int sq = 0; sq < 2; sq++) {
        const short* Qp = Qb + ((size_t)(b * 16 + h) * 2048 + qt * 256 + w * 32 + sq * 16 + l16) * 128;
        #pragma unroll
        for (int kc = 0; kc < 4; kc++)
            qfrag[sq][kc] = *(const sh8*)(Qp + kc * 32 + quad * 8);
    }

    f32x4 oacc[2][8];
    #pragma unroll
    for (int sq = 0; sq < 2; sq++)
        #pragma unroll
        for (int dt = 0; dt < 8; dt++) { oacc[sq][dt].x = 0.f; oacc[sq][dt].y = 0.f; oacc[sq][dt].z = 0.f; oacc[sq][dt].w = 0.f; }
    float lp[2] = {0.f, 0.f};

    // prefetch tile 0 (keys 0..127)
    sh8 kpre[4], vpre[4];
    #pragma unroll
    for (int j = 0; j < 4; j++) {
        kpre[j] = *(const sh8*)(Kp + (size_t)krow[j] * 128 + koff[j]);
        vpre[j] = *(const sh8*)(Vp + (size_t)krow[j] * 2048 + koff[j]);
    }

    const int iq0 = qt * 256 + w * 32 + l16;
    const int i_lo = qt * 256 + w * 32;

    for (int kt = 0; kt < 16; kt++) {
        __syncthreads();   // all waves done reading Ks/Vts of tile kt-1
        #pragma unroll
        for (int j = 0; j < 4; j++) {
            *(sh8*)&Ks[krow[j]][koff[j]]  = kpre[j];
            *(sh8*)&Vts[krow[j]][koff[j]] = vpre[j];
        }
        __syncthreads();   // staging visible
        const int ktn = (kt < 15) ? kt + 1 : 15;
        #pragma unroll
        for (int j = 0; j < 4; j++) {
            kpre[j] = *(const sh8*)(Kp + (size_t)(ktn * 128 + krow[j]) * 128 + koff[j]);
            vpre[j] = *(const sh8*)(Vp + (size_t)krow[j] * 2048 + ktn * 128 + koff[j]);
        }

        // ---- S^T = K Q^T over 8 key-subtiles ----
        f32x4 sacc[2][8];
        #pragma unroll
        for (int sq = 0; sq < 2; sq++)
            #pragma unroll
            for (int nt = 0; nt < 8; nt++) { sacc[sq][nt].x = 0.f; sacc[sq][nt].y = 0.f; sacc[sq][nt].z = 0.f; sacc[sq][nt].w = 0.f; }
        #pragma unroll
        for (int kc = 0; kc < 4; kc++) {
            #pragma unroll
            for (int nt = 0; nt < 8; nt++) {
                const sh8 kf = *(const sh8*)&Ks[nt * 16 + l16][kc * 32 + quad * 8];
                sacc[0][nt] = __builtin_amdgcn_mfma_f32_16x16x32_bf16(kf, qfrag[0][kc], sacc[0][nt], 0, 0, 0);
                sacc[1][nt] = __builtin_amdgcn_mfma_f32_16x16x32_bf16(kf, qfrag[1][kc], sacc[1][nt], 0, 0, 0);
            }
        }

        // ---- mask class per 64-key half (v9b logic, j_lo-based) ----
        float B2h[2]; bool unih[2];
        #pragma unroll
        for (int h2 = 0; h2 < 2; h2++) {
            const int j_lo = kt * 128 + h2 * 64;
            if (j_lo == 0 || j_lo + 63 <= i_lo)          { B2h[h2] = B2A; unih[h2] = true; }
            else if (j_lo > i_lo + 31 || i_lo + 31 < 64) { B2h[h2] = B2M; unih[h2] = true; }
            else                                         { B2h[h2] = B2A; unih[h2] = false; }
        }

        // ---- softmax (p = 2^(s*SC2 + B2)) + in-register layout exchange ----
        sh8 apf[2][4];
        #pragma unroll
        for (int sq = 0; sq < 2; sq++) {
            unsigned D[8][2];
            const int i_g = iq0 + sq * 16;
            #pragma unroll
            for (int h2 = 0; h2 < 2; h2++) {
                if (unih[h2]) {
                    const float B2u = B2h[h2];
                    #pragma unroll
                    for (int n4 = 0; n4 < 4; n4++) {
                        const int nt = h2 * 4 + n4;
                        float pv[4];
                        #pragma unroll
                        for (int reg = 0; reg < 4; reg++) {
                            const float p = fexp2(fmaf(sacc[sq][nt][reg], SC2, B2u));
                            lp[sq] += p;
                            pv[reg] = p;
                        }
                        D[nt][0] = pk2h(pv[0], pv[1]);
                        D[nt][1] = pk2h(pv[2], pv[3]);
                    }
                } else {
                    #pragma unroll
                    for (int n4 = 0; n4 < 4; n4++) {
                        const int nt = h2 * 4 + n4;
                        float pv[4];
                        #pragma unroll
                        for (int reg = 0; reg < 4; reg++) {
                            const int j_g = kt * 128 + nt * 16 + quad * 4 + reg;
                            const float bb = (j_g <= i_g) ? B2A : B2M;
                            const float p = fexp2(fmaf(sacc[sq][nt][reg], SC2, bb));
                            lp[sq] += p;
                            pv[reg] = p;
                        }
                        D[nt][0] = pk2h(pv[0], pv[1]);
                        D[nt][1] = pk2h(pv[2], pv[3]);
                    }
                }
            }
            #pragma unroll
            for (int kc2 = 0; kc2 < 4; kc2++) {
                unsigned dq[4];
                #pragma unroll
                for (int hh = 0; hh < 2; hh++) {
                    uv2 r = __builtin_amdgcn_permlane32_swap(
                        D[2 * kc2][hh], D[2 * kc2 + 1][hh], false, false);
                    const unsigned snd = (quad & 1) ? r[0] : r[1];
                    const unsigned R = (unsigned)__shfl_xor((int)snd, 16, 64);
                    dq[hh]     = (quad & 1) ? R : r[0];
                    dq[2 + hh] = (quad & 1) ? r[1] : R;
                }
                union { unsigned u[4]; sh8 s; } av;
                av.u[0] = dq[0]; av.u[1] = dq[1]; av.u[2] = dq[2]; av.u[3] = dq[3];
                apf[sq][kc2] = av.s;
            }
        }

        // ---- O += P V : A = apf (fp16 regs), B = V^T[d][key] fp16 ----
        #pragma unroll
        for (int kc2 = 0; kc2 < 4; kc2++) {
            const hf8 a0 = *(const hf8*)&apf[0][kc2];
            const hf8 a1 = *(const hf8*)&apf[1][kc2];
            #pragma unroll
            for (int dt = 0; dt < 8; dt++) {
                const hf8 bv = *(const hf8*)&Vts[dt * 16 + l16][kc2 * 32 + quad * 8];
                oacc[0][dt] = __builtin_amdgcn_mfma_f32_16x16x32_f16(a0, bv, oacc[0][dt], 0, 0, 0);
                oacc[1][dt] = __builtin_amdgcn_mfma_f32_16x16x32_f16(a1, bv, oacc[1][dt], 0, 0, 0);
            }
        }
    }

    #pragma unroll
    for (int sq = 0; sq < 2; sq++) {
        float l = lp[sq];
        l += __shfl_xor(l, 16, 64);
        l += __shfl_xor(l, 32, 64);
        f32x4 inv4;
        #pragma unroll
        for (int reg = 0; reg < 4; reg++)
            inv4[reg] = 1.0f / __shfl(l, quad * 4 + reg, 64);
        const size_t row0 = (size_t)b * 2048 + qt * 256 + w * 32 + sq * 16 + quad * 4;
        #pragma unroll
        for (int reg = 0; reg < 4; reg++) {
            const size_t base = (row0 + reg) * 2048 + h * 128 + l16;
            #pragma unroll
            for (int dt = 0; dt < 8; dt++)
                AOf[base + dt * 16] = (_Float16)(oacc[sq][dt][reg] * inv4[reg]);
        }
    }
}

// ---------------------------------------------------------------------------
// Output GEMM (R9/R11, passing): fp16, BK=64, swizzled LDS, 3-4 blocks/CU
// cross-block overlap, L2-resident B-panel mapping (2 n-cols x 32 m per XCD).
// ---------------------------------------------------------------------------
__global__ __launch_bounds__(256) void gemm_out_fp16(
    const _Float16* __restrict__ A, const _Float16* __restrict__ Bt,
    float* __restrict__ out)
{
    __shared__ _Float16 As[128 * 64];
    __shared__ _Float16 Bs[128 * 64];

    const int tid = threadIdx.x;
    const int w = tid >> 6, lane = tid & 63;
    const int l16 = lane & 15, quad = lane >> 4;

    const int flat0 = blockIdx.y * 16 + blockIdx.x;
    const int xcd   = flat0 & 7;
    const int i_    = flat0 >> 3;
    const int n0    = (xcd * 2 + (i_ >> 5)) * 128;
    const int m0    = (i_ & 31) * 128;

    const int wm = w & 1, wn = w >> 1;

    const int srow = lane >> 3;
    const int scol = ((lane & 7) ^ srow) * 8;
    const _Float16* ag[4]; const _Float16* bg[4];
    _Float16* al[4]; _Float16* bl[4];
    #pragma unroll
    for (int j = 0; j < 4; j++) {
        ag[j] = A  + (size_t)(m0 + w * 32 + j * 8 + srow) * 2048 + scol;
        bg[j] = Bt + (size_t)(n0 + w * 32 + j * 8 + srow) * 2048 + scol;
        al[j] = As + (w * 32 + j * 8) * 64;
        bl[j] = Bs + (w * 32 + j * 8) * 64;
    }

    f32x4 acc[4][4];
    #pragma unroll
    for (int i = 0; i < 4; i++)
        #pragma unroll
        for (int j = 0; j < 4; j++) { acc[i][j].x = 0.f; acc[i][j].y = 0.f; acc[i][j].z = 0.f; acc[i][j].w = 0.f; }

    for (int kt = 0; kt < 32; kt++) {
        __syncthreads();
        #pragma unroll
        for (int j = 0; j < 4; j++) {
            gl2lds16(ag[j], al[j]);
            gl2lds16(bg[j], bl[j]);
            ag[j] += 64; bg[j] += 64;
        }
        __syncthreads();

        hf8 af[2][4], bfr[2][4];
        #pragma unroll
        for (int half = 0; half < 2; half++) {
            #pragma unroll
            for (int mt = 0; mt < 4; mt++) {
                const int ra = wm * 64 + mt * 16 + l16;
                af[half][mt] = *(const hf8*)&As[ra * 64 + (((half << 2) + quad) ^ (l16 & 7)) * 8];
                const int rb = wn * 64 + mt * 16 + l16;
                bfr[half][mt] = *(const hf8*)&Bs[rb * 64 + (((half << 2) + quad) ^ (l16 & 7)) * 8];
            }
        }
        #pragma unroll
        for (int half = 0; half < 2; half++)
            #pragma unroll
            for (int mt = 0; mt < 4; mt++)
                #pragma unroll
                for (int nt = 0; nt < 4; nt++)
                    acc[mt][nt] = __builtin_amdgcn_mfma_f32_16x16x32_f16(af[half][mt], bfr[half][nt], acc[mt][nt], 0, 0, 0);
    }

    #pragma unroll
    for (int nt = 0; nt < 4; nt++) {
        const int n = n0 + wn * 64 + nt * 16 + l16;
        #pragma unroll
        for (int mt = 0; mt < 4; mt++) {
            #pragma unroll
            for (int reg = 0; reg < 4; reg++) {
                const int m = m0 + wm * 64 + mt * 16 + quad * 4 + reg;
                out[(size_t)m * 2048 + n] = acc[mt][nt][reg];
            }
        }
    }
}

// ---------------------------------------------------------------------------
extern "C" void kernel_launch(void* const* d_in, const int* in_sizes, int n_in,
                              void* d_out, int out_size, void* d_ws, size_t ws_size,
                              hipStream_t stream)
{
    (void)in_sizes; (void)n_in; (void)out_size; (void)ws_size;
    const float* hs   = (const float*)d_in[0];
    const float* cosp = (const float*)d_in[1];
    const float* sinp = (const float*)d_in[2];
    const float* Wq   = (const float*)d_in[3];
    const float* bq   = (const float*)d_in[4];
    const float* Wk   = (const float*)d_in[5];
    const float* bk   = (const float*)d_in[6];
    const float* Wv   = (const float*)d_in[7];
    const float* bv   = (const float*)d_in[8];
    const float* Wo   = (const float*)d_in[9];
    float* out = (float*)d_out;

    // workspace (2-byte elems), 67.1 MB total:
    short*    hs_bf = (short*)d_ws;          // 8,388,608   [4096][2048] bf16
    short*    WT    = hs_bf + 8388608;       // 6,291,456   [3072][2048] bf16
    short*    Vb    = WT + 6291456;          // 2,097,152   (B,KV,T,D) fp16 bits
    _Float16* WoT   = (_Float16*)(Vb + 2097152); // 4,194,304 [2048][2048] fp16
    short*    Qb    = (short*)(WoT + 4194304);   // 8,388,608 (B,H,T,D) bf16
    short*    Kb    = Qb + 8388608;          // 2,097,152
    short*    Vt    = Kb + 2097152;          // 2,097,152   (B,KV,D,T) fp16 bits
    // overlay (hs_bf dead after gemm_qkv): AO fp16 [4096][2048]
    _Float16* AOf = (_Float16*)hs_bf;

    prep_kernel   <<<10752, 256, 0, stream>>>(hs, hs_bf, Wq, Wk, Wv, WT, Wo, WoT);
    gemm_qkv_mfma <<<192, 512, 0, stream>>>(hs_bf, WT, bq, bk, bv, Qb, Kb, (_Float16*)Vb);
    rope_tv_kernel<<<2736, 256, 0, stream>>>(Qb, Kb, cosp, sinp, Vb, Vt);
    attn_mfma     <<<dim3(8, 16, 2), 512, 0, stream>>>(Qb, Kb, Vt, AOf);
    gemm_out_fp16 <<<dim3(16, 32), 256, 0, stream>>>(AOf, WoT, out);
}

// Round 17
// 318.222 us; speedup vs baseline: 1.0531x; 1.0531x over previous
//
#include <hip/hip_runtime.h>
#include <math.h>

#define SCALE_ 0.08838834764831845f  // 128^-0.5
#define LOG2E_ 1.4426950408889634f

typedef __attribute__((ext_vector_type(4))) float f32x4;
typedef __attribute__((ext_vector_type(8))) short sh8;   // 8 bf16 in 4 VGPRs
typedef __attribute__((ext_vector_type(4))) short sh4;
typedef __attribute__((ext_vector_type(8))) _Float16 hf8; // 8 fp16 in 4 VGPRs
typedef __attribute__((ext_vector_type(2))) unsigned uv2;

static __device__ __forceinline__ short f2bf(float f) {
    union { float f; unsigned u; } v; v.f = f;
    unsigned r = v.u + 0x7fffu + ((v.u >> 16) & 1u);   // RNE
    return (short)(r >> 16);
}
static __device__ __forceinline__ float bf2f(short s) {
    union { unsigned u; float f; } v; v.u = ((unsigned)(unsigned short)s) << 16;
    return v.f;
}
// raw 2^x (v_exp_f32)
static __device__ __forceinline__ float fexp2(float x) {
    float r; asm("v_exp_f32 %0, %1" : "=v"(r) : "v"(x)); return r;
}
// pack 2 f32 -> 2 fp16 with RNE (RTZ bias failed absmax in R6)
static __device__ __forceinline__ unsigned pk2h(float a, float b) {
    union { _Float16 h[2]; unsigned u; } c;
    c.h[0] = (_Float16)a; c.h[1] = (_Float16)b;
    return c.u;
}

// async global->LDS, 16B per lane; LDS dest = wave-uniform base + lane*16
static __device__ __forceinline__ void gl2lds16(const void* g, void* l) {
    __builtin_amdgcn_global_load_lds(
        (const __attribute__((address_space(1))) void*)g,
        (__attribute__((address_space(3))) void*)l, 16, 0, 0);
}

// ---------------------------------------------------------------------------
// Merged preprocessing (R11, passing):
//   blocks [0, 8192)        : hs fp32 -> bf16
//   blocks [8192, 9728)     : transpose+convert QKV weights -> WT bf16
//   blocks [9728, 10752)    : transpose+convert Wo -> WoT fp16
// ---------------------------------------------------------------------------
__global__ __launch_bounds__(256) void prep_kernel(
    const float* __restrict__ hs, short* __restrict__ hs_bf,
    const float* __restrict__ Wq, const float* __restrict__ Wk,
    const float* __restrict__ Wv, short* __restrict__ WT,
    const float* __restrict__ Wo, _Float16* __restrict__ WoT)
{
    __shared__ __align__(16) float Ls[64][65];
    const int bid = blockIdx.x;
    const int tid = threadIdx.x;

    if (bid < 8192) {
        const int i = bid * 256 + tid;
        float4 v = *(const float4*)(hs + (size_t)i * 4);
        sh4 o; o.x = f2bf(v.x); o.y = f2bf(v.y); o.z = f2bf(v.z); o.w = f2bf(v.w);
        *(sh4*)(hs_bf + (size_t)i * 4) = o;
        return;
    }

    if (bid < 9728) {
        const int f  = bid - 8192;
        const int k0 = (f & 31) * 64;
        const int n0 = (f >> 5) * 64;

        const float* src; int ld, col0;
        if (n0 < 2048)      { src = Wq; ld = 2048; col0 = n0; }
        else if (n0 < 2560) { src = Wk; ld = 512;  col0 = n0 - 2048; }
        else                { src = Wv; ld = 512;  col0 = n0 - 2560; }

        for (int i = tid; i < 1024; i += 256) {
            int r = i >> 4, c4 = (i & 15) * 4;
            float4 v = *(const float4*)(src + (size_t)(k0 + r) * ld + col0 + c4);
            Ls[r][c4] = v.x; Ls[r][c4 + 1] = v.y; Ls[r][c4 + 2] = v.z; Ls[r][c4 + 3] = v.w;
        }
        __syncthreads();
        for (int i = tid; i < 512; i += 256) {
            int nl = i >> 3, kk = (i & 7) * 8;
            sh8 v;
            #pragma unroll
            for (int j = 0; j < 8; j++) v[j] = f2bf(Ls[kk + j][nl]);
            *(sh8*)(WT + (size_t)(n0 + nl) * 2048 + k0 + kk) = v;
        }
        return;
    }

    {
        const int f  = bid - 9728;
        const int k0 = (f & 31) * 64;
        const int n0 = (f >> 5) * 64;

        for (int i = tid; i < 1024; i += 256) {
            int r = i >> 4, c4 = (i & 15) * 4;
            float4 v = *(const float4*)(Wo + (size_t)(k0 + r) * 2048 + n0 + c4);
            Ls[r][c4] = v.x; Ls[r][c4 + 1] = v.y; Ls[r][c4 + 2] = v.z; Ls[r][c4 + 3] = v.w;
        }
        __syncthreads();
        for (int i = tid; i < 512; i += 256) {
            int nl = i >> 3, kk = (i & 7) * 8;
            hf8 v;
            #pragma unroll
            for (int j = 0; j < 8; j++) v[j] = (_Float16)Ls[kk + j][nl];
            *(hf8*)(WoT + (size_t)(n0 + nl) * 2048 + k0 + kk) = v;
        }
    }
}

// ---------------------------------------------------------------------------
// QKV GEMM v3 (R12 EXACT, passing, best measured): 256x256 tile, BK=32,
// 8 waves, counted-vmcnt pipeline (T3/T4): 4-buffer LDS rotation, stage t+2
// during t, vmcnt(4) + raw s_barrier (t+2's loads in flight across barrier).
// ---------------------------------------------------------------------------
__global__ __launch_bounds__(512) void gemm_qkv_mfma(
    const short* __restrict__ Abf, const short* __restrict__ Bt,
    const float* __restrict__ bq, const float* __restrict__ bk,
    const float* __restrict__ bv,
    short* __restrict__ Q, short* __restrict__ K, _Float16* __restrict__ V)
{
    __shared__ short As[4][256 * 32];   // 64 KB
    __shared__ short Bs[4][256 * 32];   // 64 KB

    const int tid  = threadIdx.x;
    const int w    = tid >> 6, lane = tid & 63;
    const int l16  = lane & 15, quad = lane >> 4;
    const int wm   = w & 1, wn = w >> 1;      // 2M x 4N waves

    const int bid = blockIdx.x;               // 192 = 16m x 12n, m-major
    const int m0  = (bid & 15) * 256;
    const int n0  = (bid >> 4) * 256;

    const short* agA[2]; const short* agB[2];
    #pragma unroll
    for (int j = 0; j < 2; ++j) {
        const int row = 32 * w + 16 * j + (lane >> 2);
        const int ch  = (lane & 3) * 8;
        agA[j] = Abf + (size_t)(m0 + row) * 2048 + ch;
        agB[j] = Bt  + (size_t)(n0 + row) * 2048 + ch;
    }
    const int doff0 = (32 * w) * 32;
    const int doff1 = (32 * w + 16) * 32;

    f32x4 acc[8][4];
    #pragma unroll
    for (int i = 0; i < 8; ++i)
        #pragma unroll
        for (int j = 0; j < 4; ++j) { acc[i][j].x = 0.f; acc[i][j].y = 0.f; acc[i][j].z = 0.f; acc[i][j].w = 0.f; }

    gl2lds16(agA[0], &As[0][doff0]); gl2lds16(agB[0], &Bs[0][doff0]);
    gl2lds16(agA[1], &As[0][doff1]); gl2lds16(agB[1], &Bs[0][doff1]);
    gl2lds16(agA[0] + 32, &As[1][doff0]); gl2lds16(agB[0] + 32, &Bs[1][doff0]);
    gl2lds16(agA[1] + 32, &As[1][doff1]); gl2lds16(agB[1] + 32, &Bs[1][doff1]);
    asm volatile("s_waitcnt vmcnt(4)" ::: "memory");
    __builtin_amdgcn_s_barrier();

    for (int t = 0; t < 64; ++t) {
        const int cur = t & 3;
        const short* curA = &As[cur][0];
        const short* curB = &Bs[cur][0];

        sh8 bf_[4];
        #pragma unroll
        for (int nt = 0; nt < 4; ++nt)
            bf_[nt] = *(const sh8*)&curB[(wn * 64 + nt * 16 + l16) * 32 + quad * 8];

        sh8 af0[4];
        #pragma unroll
        for (int mt = 0; mt < 4; ++mt)
            af0[mt] = *(const sh8*)&curA[(wm * 128 + mt * 16 + l16) * 32 + quad * 8];
        if (t + 2 < 64) {
            const int nb = (t + 2) & 3;
            gl2lds16(agA[0] + (t + 2) * 32, &As[nb][doff0]);
            gl2lds16(agB[0] + (t + 2) * 32, &Bs[nb][doff0]);
        }
        __builtin_amdgcn_s_setprio(1);
        #pragma unroll
        for (int mt = 0; mt < 4; ++mt)
            #pragma unroll
            for (int nt = 0; nt < 4; ++nt)
                acc[mt][nt] = __builtin_amdgcn_mfma_f32_16x16x32_bf16(af0[mt], bf_[nt], acc[mt][nt], 0, 0, 0);
        __builtin_amdgcn_s_setprio(0);

        sh8 af1[4];
        #pragma unroll
        for (int mt = 0; mt < 4; ++mt)
            af1[mt] = *(const sh8*)&curA[(wm * 128 + (mt + 4) * 16 + l16) * 32 + quad * 8];
        if (t + 2 < 64) {
            const int nb = (t + 2) & 3;
            gl2lds16(agA[1] + (t + 2) * 32, &As[nb][doff1]);
            gl2lds16(agB[1] + (t + 2) * 32, &Bs[nb][doff1]);
        }
        __builtin_amdgcn_s_setprio(1);
        #pragma unroll
        for (int mt = 0; mt < 4; ++mt)
            #pragma unroll
            for (int nt = 0; nt < 4; ++nt)
                acc[mt + 4][nt] = __builtin_amdgcn_mfma_f32_16x16x32_bf16(af1[mt], bf_[nt], acc[mt + 4][nt], 0, 0, 0);
        __builtin_amdgcn_s_setprio(0);

        if (t < 62)       asm volatile("s_waitcnt vmcnt(4)" ::: "memory");
        else if (t == 62) asm volatile("s_waitcnt vmcnt(0)" ::: "memory");
        if (t < 63) __builtin_amdgcn_s_barrier();
    }

    #pragma unroll
    for (int nt = 0; nt < 4; ++nt) {
        const int n_g = n0 + wn * 64 + nt * 16 + l16;
        const int dl  = n_g & 127;
        int which, head; float bv_;
        if (n_g < 2048)      { which = 0; head = n_g >> 7;          bv_ = bq[n_g]; }
        else if (n_g < 2560) { which = 1; head = (n_g - 2048) >> 7; bv_ = bk[n_g - 2048]; }
        else                 { which = 2; head = (n_g - 2560) >> 7; bv_ = bv[n_g - 2560]; }
        #pragma unroll
        for (int mt = 0; mt < 8; ++mt) {
            #pragma unroll
            for (int reg = 0; reg < 4; ++reg) {
                const int m = m0 + wm * 128 + mt * 16 + quad * 4 + reg;
                const int bb = m >> 11, ts = m & 2047;
                const float fv = acc[mt][nt][reg] + bv_;
                if (which == 0)      Q[((size_t)(bb * 16 + head) * 2048 + ts) * 128 + dl] = f2bf(fv);
                else if (which == 1) K[((size_t)(bb * 4 + head) * 2048 + ts) * 128 + dl] = f2bf(fv);
                else                 V[((size_t)(bb * 4 + head) * 2048 + ts) * 128 + dl] = (_Float16)fv;
            }
        }
    }
}

// ---------------------------------------------------------------------------
// Merged RoPE + V-transpose (R11, passing):
//   blocks [0, 2480)    : RoPE in-place on Q,K (vectorized sh8)
//   blocks [2480, 2736) : transpose V (B,KV,T,D) -> Vt (B,KV,D,T)
// ---------------------------------------------------------------------------
__global__ __launch_bounds__(256) void rope_tv_kernel(
    short* __restrict__ Q, short* __restrict__ K,
    const float* __restrict__ cosp, const float* __restrict__ sinp,
    const short* __restrict__ Vb, short* __restrict__ Vt)
{
    __shared__ __align__(16) short Ls[64][136];
    const int bid = blockIdx.x;
    const int tid = threadIdx.x;

    if (bid < 2480) {
        int idx = bid * 256 + tid;
        if (idx >= 2 * 1984 * 20 * 8) return;
        const int j    = idx & 7;
        const int r1   = idx >> 3;
        const int head = r1 % 20;
        const int r2   = r1 / 20;
        const int tt   = r2 % 1984;
        const int b    = r2 / 1984;
        const int t    = 64 + tt;

        const float* cb = cosp + ((size_t)b * 1984 + tt) * 128 + j * 8;
        const float* sb = sinp + ((size_t)b * 1984 + tt) * 128 + j * 8;

        short* base;
        if (head < 16) base = Q + ((size_t)(b * 16 + head)        * 2048 + t) * 128 + j * 8;
        else           base = K + ((size_t)(b * 4  + (head - 16)) * 2048 + t) * 128 + j * 8;

        sh8 x1 = *(const sh8*)base;
        sh8 x2 = *(const sh8*)(base + 64);
        sh8 o1, o2;
        #pragma unroll
        for (int u = 0; u < 8; u++) {
            const float a  = bf2f(x1[u]);
            const float bb = bf2f(x2[u]);
            o1[u] = f2bf(a  * cb[u]      - bb * sb[u]);
            o2[u] = f2bf(bb * cb[u + 64] + a  * sb[u + 64]);
        }
        *(sh8*)base        = o1;
        *(sh8*)(base + 64) = o2;
        return;
    }

    {
        const int f   = bid - 2480;
        const int bkv = f >> 5;
        const int t0  = (f & 31) * 64;

        const short* src = Vb + ((size_t)bkv * 2048 + t0) * 128;
        for (int i = tid; i < 1024; i += 256) {
            int r = i >> 4, c = (i & 15) * 8;
            *(sh8*)&Ls[r][c] = *(const sh8*)(src + (size_t)r * 128 + c);
        }
        __syncthreads();
        short* dst = Vt + (size_t)bkv * 128 * 2048 + t0;
        for (int i = tid; i < 1024; i += 256) {
            int d = i >> 3, c = (i & 7) * 8;
            sh8 v;
            #pragma unroll
            for (int j = 0; j < 8; j++) v[j] = Ls[c + j][d];
            *(sh8*)(dst + (size_t)d * 2048 + c) = v;
        }
    }
}

// ---------------------------------------------------------------------------
// Flash attention v9b (passing, ~87us, best measured): in-register P
// exchange, wave-uniform mask base, raw v_exp_f32, RNE fp16 P, f16 PV.
// KVBLK=128 (R16) regressed via register spill (VGPR 128 + 4.6MB scratch).
// ---------------------------------------------------------------------------
#define M0_ 14.0f

__global__ __launch_bounds__(512) void attn_mfma(
    const short* __restrict__ Qb, const short* __restrict__ Kb,
    const short* __restrict__ Vt, _Float16* __restrict__ AOf)
{
    __shared__ __align__(16) short Ks[64][136];    // [key][d] bf16  17408 B
    __shared__ __align__(16) short Vts[128][72];   // [d][key] fp16  18432 B

    const int tid  = threadIdx.x;
    const int qt   = blockIdx.x;
    const int h    = blockIdx.y;
    const int b    = blockIdx.z;
    const int kvh  = h >> 2;
    const int w    = tid >> 6;
    const int lane = tid & 63;
    const int l16  = lane & 15;
    const int quad = lane >> 4;

    const float SC2 = SCALE_ * LOG2E_;
    const float B2A = (1.0f - M0_) * LOG2E_;
    const float B2M = (-M0_) * LOG2E_;

    const short* Kp = Kb + ((size_t)(b * 4 + kvh) * 2048) * 128;
    const short* Vp = Vt + ((size_t)(b * 4 + kvh) * 128) * 2048;

    int krow[2], koff[2], vrow[2], voff[2];
    #pragma unroll
    for (int j = 0; j < 2; j++) {
        const int c = tid + 512 * j;
        krow[j] = c >> 4; koff[j] = (c & 15) * 8;
        vrow[j] = c >> 3; voff[j] = (c & 7) * 8;
    }

    sh8 qfrag[2][4];
    #pragma unroll
    for (int sq = 0; sq < 2; sq++) {
        const short* Qp = Qb + ((size_t)(b * 16 + h) * 2048 + qt * 256 + w * 32 + sq * 16 + l16) * 128;
        #pragma unroll
        for (int kc = 0; kc < 4; kc++)
            qfrag[sq][kc] = *(const sh8*)(Qp + kc * 32 + quad * 8);
    }

    f32x4 oacc[2][8];
    #pragma unroll
    for (int sq = 0; sq < 2; sq++)
        #pragma unroll
        for (int dt = 0; dt < 8; dt++) { oacc[sq][dt].x = 0.f; oacc[sq][dt].y = 0.f; oacc[sq][dt].z = 0.f; oacc[sq][dt].w = 0.f; }
    float lp[2] = {0.f, 0.f};

    sh8 kpre[2], vpre[2];
    #pragma unroll
    for (int j = 0; j < 2; j++) {
        kpre[j] = *(const sh8*)(Kp + (size_t)krow[j] * 128 + koff[j]);
        vpre[j] = *(const sh8*)(Vp + (size_t)vrow[j] * 2048 + voff[j]);
    }

    const int iq0 = qt * 256 + w * 32 + l16;
    const int i_lo = qt * 256 + w * 32;

    for (int kt = 0; kt < 32; kt++) {
        __syncthreads();
        #pragma unroll
        for (int j = 0; j < 2; j++) {
            *(sh8*)&Ks[krow[j]][koff[j]]  = kpre[j];
            *(sh8*)&Vts[vrow[j]][voff[j]] = vpre[j];
        }
        __syncthreads();
        const int ktn = (kt < 31) ? kt + 1 : 31;
        #pragma unroll
        for (int j = 0; j < 2; j++) {
            kpre[j] = *(const sh8*)(Kp + (size_t)(ktn * 64 + krow[j]) * 128 + koff[j]);
            vpre[j] = *(const sh8*)(Vp + (size_t)vrow[j] * 2048 + ktn * 64 + voff[j]);
        }

        f32x4 sacc[2][4];
        #pragma unroll
        for (int sq = 0; sq < 2; sq++)
            #pragma unroll
            for (int nt = 0; nt < 4; nt++) { sacc[sq][nt].x = 0.f; sacc[sq][nt].y = 0.f; sacc[sq][nt].z = 0.f; sacc[sq][nt].w = 0.f; }
        #pragma unroll
        for (int kc = 0; kc < 4; kc++) {
            #pragma unroll
            for (int nt = 0; nt < 4; nt++) {
                const sh8 kf = *(const sh8*)&Ks[nt * 16 + l16][kc * 32 + quad * 8];
                sacc[0][nt] = __builtin_amdgcn_mfma_f32_16x16x32_bf16(kf, qfrag[0][kc], sacc[0][nt], 0, 0, 0);
                sacc[1][nt] = __builtin_amdgcn_mfma_f32_16x16x32_bf16(kf, qfrag[1][kc], sacc[1][nt], 0, 0, 0);
            }
        }

        const int j_lo = kt * 64;
        float B2u = B2A; bool uni = true;
        if (kt == 0 || j_lo + 63 <= i_lo)                  B2u = B2A;
        else if (j_lo > i_lo + 31 || i_lo + 31 < 64)       B2u = B2M;
        else uni = false;

        sh8 apf[2][2];
        #pragma unroll
        for (int sq = 0; sq < 2; sq++) {
            unsigned D[4][2];
            if (uni) {
                #pragma unroll
                for (int nt = 0; nt < 4; nt++) {
                    float pv[4];
                    #pragma unroll
                    for (int reg = 0; reg < 4; reg++) {
                        const float p = fexp2(fmaf(sacc[sq][nt][reg], SC2, B2u));
                        lp[sq] += p;
                        pv[reg] = p;
                    }
                    D[nt][0] = pk2h(pv[0], pv[1]);
                    D[nt][1] = pk2h(pv[2], pv[3]);
                }
            } else {
                const int i_g = iq0 + sq * 16;
                #pragma unroll
                for (int nt = 0; nt < 4; nt++) {
                    float pv[4];
                    #pragma unroll
                    for (int reg = 0; reg < 4; reg++) {
                        const int j_g = j_lo + nt * 16 + quad * 4 + reg;
                        const float bb = (j_g <= i_g) ? B2A : B2M;
                        const float p = fexp2(fmaf(sacc[sq][nt][reg], SC2, bb));
                        lp[sq] += p;
                        pv[reg] = p;
                    }
                    D[nt][0] = pk2h(pv[0], pv[1]);
                    D[nt][1] = pk2h(pv[2], pv[3]);
                }
            }
            #pragma unroll
            for (int kc2 = 0; kc2 < 2; kc2++) {
                unsigned dq[4];
                #pragma unroll
                for (int hh = 0; hh < 2; hh++) {
                    uv2 r = __builtin_amdgcn_permlane32_swap(
                        D[2 * kc2][hh], D[2 * kc2 + 1][hh], false, false);
                    const unsigned snd = (quad & 1) ? r[0] : r[1];
                    const unsigned R = (unsigned)__shfl_xor((int)snd, 16, 64);
                    dq[hh]     = (quad & 1) ? R : r[0];
                    dq[2 + hh] = (quad & 1) ? r[1] : R;
                }
                union { unsigned u[4]; sh8 s; } av;
                av.u[0] = dq[0]; av.u[1] = dq[1]; av.u[2] = dq[2]; av.u[3] = dq[3];
                apf[sq][kc2] = av.s;
            }
        }

        #pragma unroll
        for (int kc2 = 0; kc2 < 2; kc2++) {
            const hf8 a0 = *(const hf8*)&apf[0][kc2];
            const hf8 a1 = *(const hf8*)&apf[1][kc2];
            #pragma unroll
            for (int dt = 0; dt < 8; dt++) {
                const hf8 bv = *(const hf8*)&Vts[dt * 16 + l16][kc2 * 32 + quad * 8];
                oacc[0][dt] = __builtin_amdgcn_mfma_f32_16x16x32_f16(a0, bv, oacc[0][dt], 0, 0, 0);
                oacc[1][dt] = __builtin_amdgcn_mfma_f32_16x16x32_f16(a1, bv, oacc[1][dt], 0, 0, 0);
            }
        }
    }

    #pragma unroll
    for (int sq = 0; sq < 2; sq++) {
        float l = lp[sq];
        l += __shfl_xor(l, 16, 64);
        l += __shfl_xor(l, 32, 64);
        f32x4 inv4;
        #pragma unroll
        for (int reg = 0; reg < 4; reg++)
            inv4[reg] = 1.0f / __shfl(l, quad * 4 + reg, 64);
        const size_t row0 = (size_t)b * 2048 + qt * 256 + w * 32 + sq * 16 + quad * 4;
        #pragma unroll
        for (int reg = 0; reg < 4; reg++) {
            const size_t base = (row0 + reg) * 2048 + h * 128 + l16;
            #pragma unroll
            for (int dt = 0; dt < 8; dt++)
                AOf[base + dt * 16] = (_Float16)(oacc[sq][dt][reg] * inv4[reg]);
        }
    }
}

// ---------------------------------------------------------------------------
// Output GEMM (R9/R11, passing): fp16, BK=64, swizzled LDS, 3-4 blocks/CU
// cross-block overlap, L2-resident B-panel mapping (2 n-cols x 32 m per XCD).
// ---------------------------------------------------------------------------
__global__ __launch_bounds__(256) void gemm_out_fp16(
    const _Float16* __restrict__ A, const _Float16* __restrict__ Bt,
    float* __restrict__ out)
{
    __shared__ _Float16 As[128 * 64];
    __shared__ _Float16 Bs[128 * 64];

    const int tid = threadIdx.x;
    const int w = tid >> 6, lane = tid & 63;
    const int l16 = lane & 15, quad = lane >> 4;

    const int flat0 = blockIdx.y * 16 + blockIdx.x;
    const int xcd   = flat0 & 7;
    const int i_    = flat0 >> 3;
    const int n0    = (xcd * 2 + (i_ >> 5)) * 128;
    const int m0    = (i_ & 31) * 128;

    const int wm = w & 1, wn = w >> 1;

    const int srow = lane >> 3;
    const int scol = ((lane & 7) ^ srow) * 8;
    const _Float16* ag[4]; const _Float16* bg[4];
    _Float16* al[4]; _Float16* bl[4];
    #pragma unroll
    for (int j = 0; j < 4; j++) {
        ag[j] = A  + (size_t)(m0 + w * 32 + j * 8 + srow) * 2048 + scol;
        bg[j] = Bt + (size_t)(n0 + w * 32 + j * 8 + srow) * 2048 + scol;
        al[j] = As + (w * 32 + j * 8) * 64;
        bl[j] = Bs + (w * 32 + j * 8) * 64;
    }

    f32x4 acc[4][4];
    #pragma unroll
    for (int i = 0; i < 4; i++)
        #pragma unroll
        for (int j = 0; j < 4; j++) { acc[i][j].x = 0.f; acc[i][j].y = 0.f; acc[i][j].z = 0.f; acc[i][j].w = 0.f; }

    for (int kt = 0; kt < 32; kt++) {
        __syncthreads();
        #pragma unroll
        for (int j = 0; j < 4; j++) {
            gl2lds16(ag[j], al[j]);
            gl2lds16(bg[j], bl[j]);
            ag[j] += 64; bg[j] += 64;
        }
        __syncthreads();

        hf8 af[2][4], bfr[2][4];
        #pragma unroll
        for (int half = 0; half < 2; half++) {
            #pragma unroll
            for (int mt = 0; mt < 4; mt++) {
                const int ra = wm * 64 + mt * 16 + l16;
                af[half][mt] = *(const hf8*)&As[ra * 64 + (((half << 2) + quad) ^ (l16 & 7)) * 8];
                const int rb = wn * 64 + mt * 16 + l16;
                bfr[half][mt] = *(const hf8*)&Bs[rb * 64 + (((half << 2) + quad) ^ (l16 & 7)) * 8];
            }
        }
        #pragma unroll
        for (int half = 0; half < 2; half++)
            #pragma unroll
            for (int mt = 0; mt < 4; mt++)
                #pragma unroll
                for (int nt = 0; nt < 4; nt++)
                    acc[mt][nt] = __builtin_amdgcn_mfma_f32_16x16x32_f16(af[half][mt], bfr[half][nt], acc[mt][nt], 0, 0, 0);
    }

    #pragma unroll
    for (int nt = 0; nt < 4; nt++) {
        const int n = n0 + wn * 64 + nt * 16 + l16;
        #pragma unroll
        for (int mt = 0; mt < 4; mt++) {
            #pragma unroll
            for (int reg = 0; reg < 4; reg++) {
                const int m = m0 + wm * 64 + mt * 16 + quad * 4 + reg;
                out[(size_t)m * 2048 + n] = acc[mt][nt][reg];
            }
        }
    }
}

// ---------------------------------------------------------------------------
extern "C" void kernel_launch(void* const* d_in, const int* in_sizes, int n_in,
                              void* d_out, int out_size, void* d_ws, size_t ws_size,
                              hipStream_t stream)
{
    (void)in_sizes; (void)n_in; (void)out_size; (void)ws_size;
    const float* hs   = (const float*)d_in[0];
    const float* cosp = (const float*)d_in[1];
    const float* sinp = (const float*)d_in[2];
    const float* Wq   = (const float*)d_in[3];
    const float* bq   = (const float*)d_in[4];
    const float* Wk   = (const float*)d_in[5];
    const float* bk   = (const float*)d_in[6];
    const float* Wv   = (const float*)d_in[7];
    const float* bv   = (const float*)d_in[8];
    const float* Wo   = (const float*)d_in[9];
    float* out = (float*)d_out;

    // workspace (2-byte elems), 67.1 MB total:
    short*    hs_bf = (short*)d_ws;          // 8,388,608   [4096][2048] bf16
    short*    WT    = hs_bf + 8388608;       // 6,291,456   [3072][2048] bf16
    short*    Vb    = WT + 6291456;          // 2,097,152   (B,KV,T,D) fp16 bits
    _Float16* WoT   = (_Float16*)(Vb + 2097152); // 4,194,304 [2048][2048] fp16
    short*    Qb    = (short*)(WoT + 4194304);   // 8,388,608 (B,H,T,D) bf16
    short*    Kb    = Qb + 8388608;          // 2,097,152
    short*    Vt    = Kb + 2097152;          // 2,097,152   (B,KV,D,T) fp16 bits
    // overlay (hs_bf dead after gemm_qkv): AO fp16 [4096][2048]
    _Float16* AOf = (_Float16*)hs_bf;

    prep_kernel   <<<10752, 256, 0, stream>>>(hs, hs_bf, Wq, Wk, Wv, WT, Wo, WoT);
    gemm_qkv_mfma <<<192, 512, 0, stream>>>(hs_bf, WT, bq, bk, bv, Qb, Kb, (_Float16*)Vb);
    rope_tv_kernel<<<2736, 256, 0, stream>>>(Qb, Kb, cosp, sinp, Vb, Vt);
    attn_mfma     <<<dim3(8, 16, 2), 512, 0, stream>>>(Qb, Kb, Vt, AOf);
    gemm_out_fp16 <<<dim3(16, 32), 256, 0, stream>>>(AOf, WoT, out);
}